// Round 1
// baseline (961.266 us; speedup 1.0000x reference)
//
#include <hip/hip_runtime.h>
#include <hip/hip_bf16.h>

#define ALPHA 0.3f
#define D 128

// ---------------------------------------------------------------------------
// Kernel 1: per-edge scatter-add.
//   64 threads (1 wave) per edge; each thread handles 2 floats (float2).
//   msg = src_embedding[src_idx[e]] + edge_embedding[e]
//   atomicAdd into agg[dst_idx[e]][:], lane 0 bumps deg[dst].
// ---------------------------------------------------------------------------
__global__ void scatter_mean_kernel(const float* __restrict__ src_emb,
                                    const float* __restrict__ edge_emb,
                                    const int*   __restrict__ src_idx,
                                    const int*   __restrict__ dst_idx,
                                    float*       __restrict__ agg,   // [N, D]
                                    float*       __restrict__ deg,   // [N]
                                    int E) {
    int tid  = blockIdx.x * blockDim.x + threadIdx.x;
    int e    = tid >> 6;          // 64 lanes per edge
    int lane = tid & 63;          // handles floats [2*lane, 2*lane+1]
    if (e >= E) return;

    int s = src_idx[e];
    int d = dst_idx[e];

    const float2* sp = (const float2*)(src_emb  + (size_t)s * D);
    const float2* ep = (const float2*)(edge_emb + (size_t)e * D);
    float2 sv = sp[lane];
    float2 ev = ep[lane];

    float* ap = agg + (size_t)d * D + 2 * lane;
    atomicAdd(ap + 0, sv.x + ev.x);
    atomicAdd(ap + 1, sv.y + ev.y);

    if (lane == 0) {
        atomicAdd(deg + d, 1.0f);
    }
}

// ---------------------------------------------------------------------------
// Kernel 2: finalize.
//   out[n] = deg[n] > 0 ? ALPHA*dst[n] + (1-ALPHA)*agg[n]/deg[n] : 0
//   32 threads per node row, float4 per thread.
// ---------------------------------------------------------------------------
__global__ void finalize_kernel(const float* __restrict__ dst_emb,
                                const float* __restrict__ agg,
                                const float* __restrict__ deg,
                                float*       __restrict__ out,
                                int N) {
    int tid  = blockIdx.x * blockDim.x + threadIdx.x;
    int n    = tid >> 5;          // 32 threads per row (32 * float4 = 128)
    int lane = tid & 31;
    if (n >= N) return;

    float dg = deg[n];
    const float4* ap = (const float4*)(agg     + (size_t)n * D);
    const float4* dp = (const float4*)(dst_emb + (size_t)n * D);
    float4 o;
    if (dg > 0.0f) {
        float4 a  = ap[lane];
        float4 db = dp[lane];
        float inv = (1.0f - ALPHA) / dg;
        o.x = ALPHA * db.x + a.x * inv;
        o.y = ALPHA * db.y + a.y * inv;
        o.z = ALPHA * db.z + a.z * inv;
        o.w = ALPHA * db.w + a.w * inv;
    } else {
        o.x = o.y = o.z = o.w = 0.0f;
    }
    ((float4*)(out + (size_t)n * D))[lane] = o;
}

extern "C" void kernel_launch(void* const* d_in, const int* in_sizes, int n_in,
                              void* d_out, int out_size, void* d_ws, size_t ws_size,
                              hipStream_t stream) {
    const float* src_emb  = (const float*)d_in[0];   // [N, D]
    const float* dst_emb  = (const float*)d_in[1];   // [N, D]
    const float* edge_emb = (const float*)d_in[2];   // [E, D]
    const int*   src_idx  = (const int*)d_in[3];     // [E]
    const int*   dst_idx  = (const int*)d_in[4];     // [E]
    float*       out      = (float*)d_out;           // [N, D]

    const int N = in_sizes[0] / D;                   // 100000
    const int E = in_sizes[3];                       // 640000

    // Workspace layout: agg [N*D] f32, then deg [N] f32.
    float* agg = (float*)d_ws;
    float* deg = agg + (size_t)N * D;

    // Zero the accumulators (harness poisons ws with 0xAA before every call).
    hipMemsetAsync(d_ws, 0, ((size_t)N * D + N) * sizeof(float), stream);

    // Scatter: 64 threads per edge, 256-thread blocks -> 4 edges/block.
    {
        int threads_total = E * 64;
        int block = 256;
        int grid  = (threads_total + block - 1) / block;
        scatter_mean_kernel<<<grid, block, 0, stream>>>(
            src_emb, edge_emb, src_idx, dst_idx, agg, deg, E);
    }

    // Finalize: 32 threads per node, 256-thread blocks -> 8 nodes/block.
    {
        int threads_total = N * 32;
        int block = 256;
        int grid  = (threads_total + block - 1) / block;
        finalize_kernel<<<grid, block, 0, stream>>>(
            dst_emb, agg, deg, out, N);
    }
}

// Round 2
// 604.763 us; speedup vs baseline: 1.5895x; 1.5895x over previous
//
#include <hip/hip_runtime.h>
#include <hip/hip_bf16.h>

#define ALPHA 0.3f
#define D 128

// ---------------------------------------------------------------------------
// Pipeline: count degrees -> allocate contiguous slot ranges per node
// (block-scan + 1 atomic/block) -> scatter edge ids into CSR -> one wave per
// node gathers+reduces its edges in registers, fused with finalize.
// No float atomics anywhere; all data-plane traffic is plain loads/stores.
// ---------------------------------------------------------------------------

__global__ void count_kernel(const int* __restrict__ dst_idx,
                             int* __restrict__ deg, int E) {
    int e = blockIdx.x * blockDim.x + threadIdx.x;
    if (e < E) atomicAdd(&deg[dst_idx[e]], 1);
}

// Per-block exclusive scan of degrees; one global atomic per block allocates
// the block's slot range. Node->range assignment is nondeterministic but
// disjoint and complete, which is all the gather needs.
__global__ void alloc_kernel(const int* __restrict__ deg,
                             int* __restrict__ start,
                             int* __restrict__ cursor,
                             int* __restrict__ counter, int N) {
    __shared__ int sdata[256];
    __shared__ int sbase;
    int t = threadIdx.x;
    int n = blockIdx.x * 256 + t;
    int val = (n < N) ? deg[n] : 0;
    sdata[t] = val;
    __syncthreads();
    for (int off = 1; off < 256; off <<= 1) {
        int x = 0;
        if (t >= off) x = sdata[t - off];
        __syncthreads();
        sdata[t] += x;
        __syncthreads();
    }
    if (t == 255) sbase = atomicAdd(counter, sdata[255]);
    __syncthreads();
    int excl = sdata[t] - val;   // exclusive prefix within block
    if (n < N) {
        int s = sbase + excl;
        start[n]  = s;
        cursor[n] = s;
    }
}

__global__ void scatter_ids_kernel(const int* __restrict__ src_idx,
                                   const int* __restrict__ dst_idx,
                                   int* __restrict__ cursor,
                                   int* __restrict__ perm_e,
                                   int* __restrict__ perm_s, int E) {
    int e = blockIdx.x * blockDim.x + threadIdx.x;
    if (e >= E) return;
    int d = dst_idx[e];
    int pos = atomicAdd(&cursor[d], 1);
    perm_e[pos] = e;            // edge id
    perm_s[pos] = src_idx[e];   // pre-gathered src index (kills a dependent load)
}

// One wave (64 lanes) per node, float2 per lane = full 512B row per access.
// n is forced wave-uniform so deg/start/perm loads become scalar loads.
__global__ void gather_finalize_kernel(const float* __restrict__ src_emb,
                                       const float* __restrict__ dst_emb,
                                       const float* __restrict__ edge_emb,
                                       const int* __restrict__ deg,
                                       const int* __restrict__ start,
                                       const int* __restrict__ perm_e,
                                       const int* __restrict__ perm_s,
                                       float* __restrict__ out, int N) {
    int wid = blockIdx.x * (blockDim.x >> 6) + (threadIdx.x >> 6);
    int n = __builtin_amdgcn_readfirstlane(wid);
    if (n >= N) return;
    int lane = threadIdx.x & 63;

    int d  = deg[n];
    int s0 = start[n];

    float accx = 0.f, accy = 0.f;
    for (int i = 0; i < d; ++i) {
        int eid  = perm_e[s0 + i];
        int sidx = perm_s[s0 + i];
        float2 ev = ((const float2*)(edge_emb + (size_t)eid  * D))[lane];
        float2 sv = ((const float2*)(src_emb  + (size_t)sidx * D))[lane];
        accx += ev.x + sv.x;
        accy += ev.y + sv.y;
    }

    float2 o;
    if (d > 0) {
        float2 dv = ((const float2*)(dst_emb + (size_t)n * D))[lane];
        float inv = (1.0f - ALPHA) / (float)d;
        o.x = ALPHA * dv.x + accx * inv;
        o.y = ALPHA * dv.y + accy * inv;
    } else {
        o.x = 0.f; o.y = 0.f;
    }
    ((float2*)(out + (size_t)n * D))[lane] = o;
}

extern "C" void kernel_launch(void* const* d_in, const int* in_sizes, int n_in,
                              void* d_out, int out_size, void* d_ws, size_t ws_size,
                              hipStream_t stream) {
    const float* src_emb  = (const float*)d_in[0];   // [N, D]
    const float* dst_emb  = (const float*)d_in[1];   // [N, D]
    const float* edge_emb = (const float*)d_in[2];   // [E, D]
    const int*   src_idx  = (const int*)d_in[3];     // [E]
    const int*   dst_idx  = (const int*)d_in[4];     // [E]
    float*       out      = (float*)d_out;           // [N, D]

    const int N = in_sizes[0] / D;                   // 100000
    const int E = in_sizes[3];                       // 640000

    // Workspace layout (all int32):
    //   deg[N] | counter[1] | start[N] | cursor[N] | perm_e[E] | perm_s[E]
    int* deg     = (int*)d_ws;
    int* counter = deg + N;
    int* start   = counter + 1;
    int* cursor  = start + N;
    int* perm_e  = cursor + N;
    int* perm_s  = perm_e + E;

    // Zero only deg + counter (harness poisons ws with 0xAA each call).
    hipMemsetAsync(d_ws, 0, (size_t)(N + 1) * sizeof(int), stream);

    int blkE = (E + 255) / 256;
    int blkN = (N + 255) / 256;

    count_kernel<<<blkE, 256, 0, stream>>>(dst_idx, deg, E);
    alloc_kernel<<<blkN, 256, 0, stream>>>(deg, start, cursor, counter, N);
    scatter_ids_kernel<<<blkE, 256, 0, stream>>>(src_idx, dst_idx, cursor,
                                                 perm_e, perm_s, E);

    // 4 waves per 256-thread block -> 4 nodes/block.
    int grid = (N + 3) / 4;
    gather_finalize_kernel<<<grid, 256, 0, stream>>>(
        src_emb, dst_emb, edge_emb, deg, start, perm_e, perm_s, out, N);
}

// Round 3
// 577.166 us; speedup vs baseline: 1.6655x; 1.0478x over previous
//
#include <hip/hip_runtime.h>
#include <hip/hip_bf16.h>

#define ALPHA 0.3f
#define D 128

typedef float v2f __attribute__((ext_vector_type(2)));

__device__ __forceinline__ v2f ldnt2(const float* p) {
    return __builtin_nontemporal_load((const v2f*)p);
}
__device__ __forceinline__ v2f ld2(const float* p) {
    return *(const v2f*)p;
}

// ---------------------------------------------------------------------------
// Pipeline: count degrees -> allocate contiguous slot ranges per node
// (block-scan + 1 atomic/block) -> scatter packed (edge,src) ids into CSR ->
// one wave per node gathers+reduces in registers, fused with finalize.
// No float atomics; data plane is plain coalesced loads/stores.
// ---------------------------------------------------------------------------

__global__ void count_kernel(const int* __restrict__ dst_idx,
                             int* __restrict__ deg, int E) {
    int e = blockIdx.x * blockDim.x + threadIdx.x;
    if (e < E) atomicAdd(&deg[dst_idx[e]], 1);
}

__global__ void alloc_kernel(const int* __restrict__ deg,
                             int* __restrict__ start,
                             int* __restrict__ cursor,
                             int* __restrict__ counter, int N) {
    __shared__ int sdata[256];
    __shared__ int sbase;
    int t = threadIdx.x;
    int n = blockIdx.x * 256 + t;
    int val = (n < N) ? deg[n] : 0;
    sdata[t] = val;
    __syncthreads();
    for (int off = 1; off < 256; off <<= 1) {
        int x = 0;
        if (t >= off) x = sdata[t - off];
        __syncthreads();
        sdata[t] += x;
        __syncthreads();
    }
    if (t == 255) sbase = atomicAdd(counter, sdata[255]);
    __syncthreads();
    int excl = sdata[t] - val;
    if (n < N) {
        int s = sbase + excl;
        start[n]  = s;
        cursor[n] = s;
    }
}

__global__ void scatter_ids_kernel(const int* __restrict__ src_idx,
                                   const int* __restrict__ dst_idx,
                                   int* __restrict__ cursor,
                                   int2* __restrict__ perm, int E) {
    int e = blockIdx.x * blockDim.x + threadIdx.x;
    if (e >= E) return;
    int d = dst_idx[e];
    int pos = atomicAdd(&cursor[d], 1);
    perm[pos] = make_int2(e, src_idx[e]);   // packed: one 8B write, one 8B read later
}

// One wave (64 lanes) per node, float2 per lane = full 512B row per access.
// Loop unrolled x4 with branchless masked remainder so 8 row-loads are in
// flight per iteration (latency chain ~d/4 instead of d).
__global__ void gather_finalize_kernel(const float* __restrict__ src_emb,
                                       const float* __restrict__ dst_emb,
                                       const float* __restrict__ edge_emb,
                                       const int*  __restrict__ deg,
                                       const int*  __restrict__ start,
                                       const int2* __restrict__ perm,
                                       float* __restrict__ out, int N) {
    int wid = blockIdx.x * (blockDim.x >> 6) + (threadIdx.x >> 6);
    int n = __builtin_amdgcn_readfirstlane(wid);
    if (n >= N) return;
    int lane = threadIdx.x & 63;
    int fo   = 2 * lane;                 // feature offset for this lane

    int d  = deg[n];
    int s0 = start[n];

    float accx = 0.f, accy = 0.f;

    for (int i = 0; i < d; i += 4) {
        int dm1 = d - 1;
        int i1 = (i + 1 < d) ? i + 1 : dm1;
        int i2 = (i + 2 < d) ? i + 2 : dm1;
        int i3 = (i + 3 < d) ? i + 3 : dm1;
        float m1 = (i + 1 < d) ? 1.f : 0.f;
        float m2 = (i + 2 < d) ? 1.f : 0.f;
        float m3 = (i + 3 < d) ? 1.f : 0.f;

        int2 p0 = perm[s0 + i];
        int2 p1 = perm[s0 + i1];
        int2 p2 = perm[s0 + i2];
        int2 p3 = perm[s0 + i3];

        v2f e0 = ldnt2(edge_emb + (size_t)p0.x * D + fo);
        v2f s0v = ld2(src_emb  + (size_t)p0.y * D + fo);
        v2f e1 = ldnt2(edge_emb + (size_t)p1.x * D + fo);
        v2f s1v = ld2(src_emb  + (size_t)p1.y * D + fo);
        v2f e2 = ldnt2(edge_emb + (size_t)p2.x * D + fo);
        v2f s2v = ld2(src_emb  + (size_t)p2.y * D + fo);
        v2f e3 = ldnt2(edge_emb + (size_t)p3.x * D + fo);
        v2f s3v = ld2(src_emb  + (size_t)p3.y * D + fo);

        accx += (e0.x + s0v.x);
        accy += (e0.y + s0v.y);
        accx += m1 * (e1.x + s1v.x);
        accy += m1 * (e1.y + s1v.y);
        accx += m2 * (e2.x + s2v.x);
        accy += m2 * (e2.y + s2v.y);
        accx += m3 * (e3.x + s3v.x);
        accy += m3 * (e3.y + s3v.y);
    }

    v2f o;
    if (d > 0) {
        v2f dv = ld2(dst_emb + (size_t)n * D + fo);
        float inv = (1.0f - ALPHA) / (float)d;
        o.x = ALPHA * dv.x + accx * inv;
        o.y = ALPHA * dv.y + accy * inv;
    } else {
        o.x = 0.f; o.y = 0.f;
    }
    __builtin_nontemporal_store(o, (v2f*)(out + (size_t)n * D + fo));
}

extern "C" void kernel_launch(void* const* d_in, const int* in_sizes, int n_in,
                              void* d_out, int out_size, void* d_ws, size_t ws_size,
                              hipStream_t stream) {
    const float* src_emb  = (const float*)d_in[0];   // [N, D]
    const float* dst_emb  = (const float*)d_in[1];   // [N, D]
    const float* edge_emb = (const float*)d_in[2];   // [E, D]
    const int*   src_idx  = (const int*)d_in[3];     // [E]
    const int*   dst_idx  = (const int*)d_in[4];     // [E]
    float*       out      = (float*)d_out;           // [N, D]

    const int N = in_sizes[0] / D;                   // 100000
    const int E = in_sizes[3];                       // 640000

    // Workspace layout: perm[E] int2 (8B-aligned, first) | deg[N] | counter[1]
    //                   | start[N] | cursor[N]
    int2* perm    = (int2*)d_ws;
    int*  deg     = (int*)(perm + E);
    int*  counter = deg + N;
    int*  start   = counter + 1;
    int*  cursor  = start + N;

    // Zero only deg + counter (harness poisons ws with 0xAA each call).
    hipMemsetAsync(deg, 0, (size_t)(N + 1) * sizeof(int), stream);

    int blkE = (E + 255) / 256;
    int blkN = (N + 255) / 256;

    count_kernel<<<blkE, 256, 0, stream>>>(dst_idx, deg, E);
    alloc_kernel<<<blkN, 256, 0, stream>>>(deg, start, cursor, counter, N);
    scatter_ids_kernel<<<blkE, 256, 0, stream>>>(src_idx, dst_idx, cursor,
                                                 perm, E);

    // 4 waves per 256-thread block -> 4 nodes/block.
    int grid = (N + 3) / 4;
    gather_finalize_kernel<<<grid, 256, 0, stream>>>(
        src_emb, dst_emb, edge_emb, deg, start, perm, out, N);
}